// Round 1
// baseline (600.037 us; speedup 1.0000x reference)
//
#include <hip/hip_runtime.h>
#include <stdint.h>

#define NROWS 500000
#define FDIM 132
// D_IN = 136, M_TOT = 24, segments start {0,3,8,15} len {3,5,7,9}

typedef unsigned short u16;
typedef unsigned int   u32;

typedef __attribute__((ext_vector_type(8))) u16    us8;
typedef __attribute__((ext_vector_type(4))) u16    us4;
typedef __attribute__((ext_vector_type(8))) __bf16 bf16x8;
typedef __attribute__((ext_vector_type(4))) float  f32x4;

__device__ __forceinline__ u16 f2bf(float f) {
    u32 u = __builtin_bit_cast(u32, f);
    u = u + 0x7FFFu + ((u >> 16) & 1u);   // round-to-nearest-even
    return (u16)(u >> 16);
}
__device__ __forceinline__ float bf2f(u16 h) {
    return __builtin_bit_cast(float, (u32)h << 16);
}

// ---------------- pre-kernel: W (f32 [136][136], row=k) -> Wt bf16 [144][128] (row=n, col=k) ----
__global__ __launch_bounds__(256) void wconv_kernel(const float* __restrict__ W,
                                                    u16* __restrict__ wt) {
    int id = blockIdx.x * 256 + threadIdx.x;     // 144*128 = 18432 ids, grid=72
    int n = id >> 7, k = id & 127;
    float v = (n < 136) ? W[k * 136 + n] : 0.0f; // zero-pad cols 136..143
    wt[id] = f2bf(v);
}

// ---------------- main kernel: 64 rows / block, 256 threads (4 waves x 16 rows) ----------------
__global__ __launch_bounds__(256, 2) void exch_kernel(const float* __restrict__ x,
                                                      const float* __restrict__ ev,
                                                      const float* __restrict__ W,
                                                      const float* __restrict__ b,
                                                      const u16* __restrict__ wt,
                                                      float* __restrict__ out) {
    // LDS: 36864 + 16384 + 4352 + 6144 + 512 + 1024 = 65280 B  (<= 64 KiB)
    __shared__ __align__(16) u16   Wt_sh[144 * 128];  // bf16, row n, 16B-chunk XOR swizzled
    __shared__ __align__(16) u16   A_sh[64 * 128];    // bf16 x tile, swizzled
    __shared__ __align__(16) float Wtl_sh[8 * 136];   // f32 W rows k=128..135
    __shared__ __align__(16) float ev_sh[64 * 24];    // f32
    __shared__ __align__(16) u16   xt_sh[64 * 4];     // bf16 x[:,128..132)
    __shared__ __align__(16) float contr_sh[64 * 4];  // f32 contr; reused as cev after barrier

    const int tid  = threadIdx.x;
    const int row0 = blockIdx.x * 64;

    // ---- stage Wt: 2304 chunks of 16B, 9 per thread, swizzle phys = ch ^ (n&7) ----
#pragma unroll
    for (int i = 0; i < 9; ++i) {
        int c = tid + i * 256;
        us8 v = *(const us8*)(wt + c * 8);
        int n = c >> 4, ch = c & 15;
        int phys = ch ^ (n & 7);
        *(us8*)(&Wt_sh[n * 128 + phys * 8]) = v;
    }

    // ---- stage A: rows 0..63, 16 chunks of 8 floats -> bf16 ----
#pragma unroll
    for (int i = 0; i < 4; ++i) {
        int c = tid + i * 256;
        int row = c >> 4, ch = c & 15;
        int grow = row0 + row;
        f32x4 a0 = {0.f, 0.f, 0.f, 0.f}, a1 = {0.f, 0.f, 0.f, 0.f};
        if (grow < NROWS) {
            const float* p = x + (size_t)grow * FDIM + ch * 8;
            a0 = *(const f32x4*)p;
            a1 = *(const f32x4*)(p + 4);
        }
        us8 v;
        v[0] = f2bf(a0[0]); v[1] = f2bf(a0[1]); v[2] = f2bf(a0[2]); v[3] = f2bf(a0[3]);
        v[4] = f2bf(a1[0]); v[5] = f2bf(a1[1]); v[6] = f2bf(a1[2]); v[7] = f2bf(a1[3]);
        int phys = ch ^ (row & 7);
        *(us8*)(&A_sh[row * 128 + phys * 8]) = v;
    }

    // ---- stage x tail (k=128..131) as bf16 ----
    if (tid < 64) {
        int grow = row0 + tid;
        f32x4 a = {0.f, 0.f, 0.f, 0.f};
        if (grow < NROWS) a = *(const f32x4*)(x + (size_t)grow * FDIM + 128);
        us4 v;
        v[0] = f2bf(a[0]); v[1] = f2bf(a[1]); v[2] = f2bf(a[2]); v[3] = f2bf(a[3]);
        *(us4*)(&xt_sh[tid * 4]) = v;
    }

    // ---- stage ev: 384 float4 tasks ----
#pragma unroll
    for (int i = 0; i < 2; ++i) {
        int c = tid + i * 256;
        if (c < 384) {
            int row = c / 6, j4 = c % 6;
            int grow = row0 + row;
            f32x4 e = {0.f, 0.f, 0.f, 0.f};
            if (grow < NROWS) e = *(const f32x4*)(ev + (size_t)grow * 24 + j4 * 4);
            *(f32x4*)(&ev_sh[row * 24 + j4 * 4]) = e;
        }
    }

    // ---- stage W tail rows (k=128..135, contiguous in W) as f32: 272 float4 tasks ----
    {
        int c = tid;
        f32x4 v = *(const f32x4*)(W + 128 * 136 + c * 4);
        *(f32x4*)(&Wtl_sh[c * 4]) = v;
        if (tid < 16) {
            int c2 = tid + 256;
            f32x4 v2 = *(const f32x4*)(W + 128 * 136 + c2 * 4);
            *(f32x4*)(&Wtl_sh[c2 * 4]) = v2;
        }
    }

    __syncthreads();

    // ---- contr: 64 rows x 4 segments, one thread each ----
    {
        int r = tid >> 2, d = tid & 3;
        int st = d * (d + 2);      // 0,3,8,15
        int len = 2 * d + 3;       // 3,5,7,9
        float s = 0.f;
        for (int j = 0; j < len; ++j) {
            float v = ev_sh[r * 24 + st + j];
            s += v * v;
        }
        contr_sh[r * 4 + d] = s;
    }

    // ---- MFMA: wave w does rows [w*16, w*16+16), 9 col tiles, K = 4 x 32 ----
    const int lane = tid & 63;
    const int w    = tid >> 6;
    const int ln   = lane & 15;
    const int q    = lane >> 4;

    f32x4 acc[9];
#pragma unroll
    for (int t = 0; t < 9; ++t) acc[t] = (f32x4){0.f, 0.f, 0.f, 0.f};

#pragma unroll
    for (int kc = 0; kc < 4; ++kc) {
        int phys = (kc * 4 + q) ^ (ln & 7);
        int off  = ln * 128 + phys * 8;    // u16 elements
        bf16x8 a = __builtin_bit_cast(bf16x8, *(const us8*)(&A_sh[w * 2048 + off]));
#pragma unroll
        for (int t = 0; t < 9; ++t) {
            bf16x8 bb = __builtin_bit_cast(bf16x8, *(const us8*)(&Wt_sh[t * 2048 + off]));
            acc[t] = __builtin_amdgcn_mfma_f32_16x16x32_bf16(a, bb, acc[t], 0, 0, 0);
        }
    }

    __syncthreads();   // orders contr writes before epilogue reads

    // ---- epilogue A: exact fp32 tail  y += xt*W[128..132) + contr*W[132..136) + b ----
    float xtv[4][4], cv[4][4];
#pragma unroll
    for (int r = 0; r < 4; ++r) {
        int row = w * 16 + q * 4 + r;
        us4 xr = *(const us4*)(&xt_sh[row * 4]);
#pragma unroll
        for (int i = 0; i < 4; ++i) xtv[r][i] = bf2f(xr[i]);
        f32x4 c4 = *(const f32x4*)(&contr_sh[row * 4]);
#pragma unroll
        for (int d = 0; d < 4; ++d) cv[r][d] = c4[d];
    }

#pragma unroll
    for (int t = 0; t < 9; ++t) {
        int col = t * 16 + ln;
        float wt8[8];
        float bias = 0.f;
        if (col < 136) {
#pragma unroll
            for (int i = 0; i < 8; ++i) wt8[i] = Wtl_sh[i * 136 + col];
            bias = b[col];
        } else {
#pragma unroll
            for (int i = 0; i < 8; ++i) wt8[i] = 0.f;
        }
#pragma unroll
        for (int r = 0; r < 4; ++r) {
            float y = acc[t][r] + bias;
#pragma unroll
            for (int i = 0; i < 4; ++i) y += xtv[r][i] * wt8[i];
#pragma unroll
            for (int d = 0; d < 4; ++d) y += cv[r][d] * wt8[4 + d];
            acc[t][r] = y;
        }
    }

    __syncthreads();   // everyone done reading contr_sh before cev overwrites it

    // ---- epilogue B: store cx, stash cev into contr_sh ----
#pragma unroll
    for (int t = 0; t < 9; ++t) {
        int col = t * 16 + ln;
#pragma unroll
        for (int r = 0; r < 4; ++r) {
            int row  = w * 16 + q * 4 + r;
            int grow = row0 + row;
            float y  = acc[t][r];
            if (col < FDIM) {
                if (grow < NROWS) out[(size_t)grow * FDIM + col] = y;
            } else if (col < 136) {
                contr_sh[row * 4 + (col - FDIM)] = y;   // cev
            }
        }
    }

    __syncthreads();

    // ---- epilogue C: out1[n,m] = cev[n, seg(m)] * ev[n,m], float4 stores ----
#pragma unroll
    for (int i = 0; i < 2; ++i) {
        int c = tid + i * 256;
        if (c < 384) {
            int row = c / 6, j4 = c % 6;
            int grow = row0 + row;
            if (grow < NROWS) {
                f32x4 e = *(const f32x4*)(&ev_sh[row * 24 + j4 * 4]);
                f32x4 o;
#pragma unroll
                for (int u = 0; u < 4; ++u) {
                    int m = j4 * 4 + u;
                    int d = (m < 3) ? 0 : (m < 8) ? 1 : (m < 15) ? 2 : 3;
                    o[u] = contr_sh[row * 4 + d] * e[u];
                }
                *(f32x4*)(out + (size_t)NROWS * FDIM + (size_t)grow * 24 + j4 * 4) = o;
            }
        }
    }
}

extern "C" void kernel_launch(void* const* d_in, const int* in_sizes, int n_in,
                              void* d_out, int out_size, void* d_ws, size_t ws_size,
                              hipStream_t stream) {
    const float* x  = (const float*)d_in[0];
    const float* ev = (const float*)d_in[1];
    const float* W  = (const float*)d_in[2];
    const float* b  = (const float*)d_in[3];
    u16* wt = (u16*)d_ws;   // needs 36864 B

    wconv_kernel<<<72, 256, 0, stream>>>(W, wt);
    int nblk = (NROWS + 63) / 64;   // 7813
    exch_kernel<<<nblk, 256, 0, stream>>>(x, ev, W, b, wt, (float*)d_out);
}